// Round 7
// baseline (250.555 us; speedup 1.0000x reference)
//
#include <hip/hip_runtime.h>
#include <hip/hip_bf16.h>

#define T_TOK 4096
#define H_DIM 1024
#define E_NUM 8
#define I_DIM 1024
#define PAD_CAP 9216   // 72 * 128 >= 8192 + 8*127
#define RBLK 16        // router blocks (256 tokens each)
#define CONVB 14336    // conversion blocks (2048 elems each)
#define ZEROB 2048     // out-zeroing blocks (2048 floats each)

typedef __attribute__((ext_vector_type(4))) float f32x4;
typedef __attribute__((ext_vector_type(8))) short bf16x8;

__device__ __forceinline__ unsigned short f2b(float f) {
  union { float f; unsigned int u; } v; v.f = f;
  unsigned int r = v.u + 0x7fffu + ((v.u >> 16) & 1u);  // RNE to bf16
  return (unsigned short)(r >> 16);
}

__device__ __forceinline__ void async_copy16(const void* g, void* l) {
  __builtin_amdgcn_global_load_lds(
      (const __attribute__((address_space(1))) void*)g,
      (__attribute__((address_space(3))) void*)l, 16, 0, 0);
}

// ---------------- prep: route-count (16 blks) + f32->bf16 conv + out-zero ------
// One dispatch does all preprocessing: per-dispatch fixed cost (~13 us measured
// across rounds 2/6) makes kernel-count the lever here. Routing latency hides
// under the BW-bound conversion. cnt[16][8] written non-atomically.
__global__ __launch_bounds__(256) void k_prep(
    const float* __restrict__ x, const float* __restrict__ logits,
    const float* __restrict__ scale,
    const float* __restrict__ w13, const float* __restrict__ w2,
    unsigned short* __restrict__ xb, unsigned short* __restrict__ w13b,
    unsigned short* __restrict__ w2b,
    int* __restrict__ tids, float* __restrict__ cw, int* __restrict__ cnt,
    float* __restrict__ out) {
  const int b = blockIdx.x;
  const int tid = threadIdx.x;
  if (b < RBLK) {
    __shared__ int s_cnt[E_NUM];
    if (tid < E_NUM) s_cnt[tid] = 0;
    __syncthreads();
    int t = b * 256 + tid;
    float l[E_NUM];
    *(float4*)(l)     = *(const float4*)(logits + (size_t)t * E_NUM);
    *(float4*)(l + 4) = *(const float4*)(logits + (size_t)t * E_NUM + 4);
    float m = l[0];
#pragma unroll
    for (int i = 1; i < E_NUM; ++i) m = fmaxf(m, l[i]);
    float p[E_NUM]; float s = 0.f;
#pragma unroll
    for (int i = 0; i < E_NUM; ++i) { p[i] = expf(l[i] - m); s += p[i]; }
    int i0 = 0; float b0 = l[0];
#pragma unroll
    for (int i = 1; i < E_NUM; ++i) if (l[i] > b0) { b0 = l[i]; i0 = i; }
    int i1 = -1; float b1 = -1e30f;
#pragma unroll
    for (int i = 0; i < E_NUM; ++i) if (i != i0 && l[i] > b1) { b1 = l[i]; i1 = i; }
    float g0 = p[i0] / s, g1 = p[i1] / s;
    float r = g0 + g1;
    cw[t * 2]     = g0 / r * scale[i0];
    cw[t * 2 + 1] = g1 / r * scale[i1];
    tids[t * 2] = i0; tids[t * 2 + 1] = i1;
    atomicAdd(&s_cnt[i0], 1);
    atomicAdd(&s_cnt[i1], 1);
    __syncthreads();
    if (tid < E_NUM) cnt[b * E_NUM + tid] = s_cnt[tid];
    return;
  }
  if (b < RBLK + CONVB) {
    const int cb = b - RBLK;
    const float* src; unsigned short* dst; size_t base;
    if (cb < 2048)       { src = x;   dst = xb;   base = (size_t)cb * 2048; }
    else if (cb < 10240) { src = w13; dst = w13b; base = (size_t)(cb - 2048) * 2048; }
    else                 { src = w2;  dst = w2b;  base = (size_t)(cb - 10240) * 2048; }
    size_t i = base + (size_t)tid * 8;
    float4 f0 = *(const float4*)(src + i);
    float4 f1 = *(const float4*)(src + i + 4);
    uint4 pk;
    pk.x = (unsigned)f2b(f0.x) | ((unsigned)f2b(f0.y) << 16);
    pk.y = (unsigned)f2b(f0.z) | ((unsigned)f2b(f0.w) << 16);
    pk.z = (unsigned)f2b(f1.x) | ((unsigned)f2b(f1.y) << 16);
    pk.w = (unsigned)f2b(f1.z) | ((unsigned)f2b(f1.w) << 16);
    *(uint4*)(dst + i) = pk;
    return;
  }
  // zero out (gemm2 accumulates into it atomically)
  const int zb = b - RBLK - CONVB;
  size_t i = (size_t)zb * 2048 + (size_t)tid * 8;
  float4 z = {0.f, 0.f, 0.f, 0.f};
  *(float4*)(out + i) = z;
  *(float4*)(out + i + 4) = z;
}

// ---------------- scatter: redundant in-block scan + rank -> perm/inv + pad-fill
// Each of 16 blocks recomputes the tiny 16x8 scan from cnt (L2-resident) —
// cheaper than a separate scan dispatch (~13 us fixed cost per dispatch).
__global__ __launch_bounds__(256) void k_scatter16(
    const int* __restrict__ cnt, const int* __restrict__ tids,
    int* __restrict__ pad_off, int* __restrict__ perm, int* __restrict__ inv) {
  __shared__ int l_cnt[E_NUM];
  __shared__ int s_base[E_NUM];                 // this block's start per expert
  __shared__ int s_off[E_NUM + 1], s_tot[E_NUM];
  const int b = blockIdx.x, tid = threadIdx.x;
  if (tid < E_NUM) l_cnt[tid] = 0;
  if (tid == 0) {
    int off = 0;
    for (int e = 0; e < E_NUM; ++e) {
      int tot = 0, mine = 0;
      for (int k = 0; k < RBLK; ++k) {
        if (k == b) mine = tot;
        tot += cnt[k * E_NUM + e];
      }
      s_tot[e] = tot;
      s_off[e] = off;
      s_base[e] = off + mine;
      off += (tot + 127) & ~127;
    }
    s_off[E_NUM] = off;
    if (b == 0) {
      for (int e = 0; e <= E_NUM; ++e) pad_off[e] = s_off[e];
    }
  }
  __syncthreads();
  int t = b * 256 + tid;
  int i0 = tids[t * 2], i1 = tids[t * 2 + 1];
  int r0 = atomicAdd(&l_cnt[i0], 1);
  int s0 = s_base[i0] + r0;
  perm[s0] = t * 2; inv[t * 2] = s0;
  int r1 = atomicAdd(&l_cnt[i1], 1);
  int s1 = s_base[i1] + r1;
  perm[s1] = t * 2 + 1; inv[t * 2 + 1] = s1;
  // pad-fill, distributed across the 16 blocks (4096 threads total)
  int gid = b * 256 + tid;
  for (int e = 0; e < E_NUM; ++e) {
    int start = s_off[e] + s_tot[e];
    int end   = s_off[e + 1];
    for (int i = start + gid; i < end; i += RBLK * 256) perm[i] = -1;
  }
}

// ---------------- GEMM1: h = gelu(x@w1^T) * (x@w3^T) ----------------
// Grid dim3(16, 72), blockIdx.x = col-block (FAST): round-robin dispatch pins
// cb -> XCD, so each (expert, cb) w13 slice stays in one XCD's L2. Do NOT
// swizzle blockIdx (round 3: FETCH 194 MB, 2x slower).
// __launch_bounds__(256, 2): LDS (64 KB) caps residency at 2 blocks/CU, so
// asking for more (round 3/4's (256,4)) only squeezes VGPRs 72->64 and loses
// K-loop latency-hiding ILP — measured 55 -> 94 us regression. Keep at 2.
// 128 padded rows x 64 unique i-cols (128 MFMA cols: 64 w1 ++ 64 w3 rows
// interleaved in 32-row segments). Wave (wm,wn) 2x2; ni 0,1 = g, ni 2,3 = u.
__global__ __launch_bounds__(256, 2) void k_gemm1(
    const unsigned short* __restrict__ xbf,
    const unsigned short* __restrict__ w13b,
    const int* __restrict__ perm, const int* __restrict__ pad_off,
    unsigned short* __restrict__ h_buf) {
  __shared__ __align__(16) unsigned short a_lds[128 * 64];
  __shared__ __align__(16) unsigned short b_lds[128 * 64];
  const int tid = threadIdx.x;
  const int wave = tid >> 6, lane = tid & 63;
  const int row0 = blockIdx.y * 128;
  if (row0 >= pad_off[E_NUM]) return;
  int e = 0;
#pragma unroll
  for (int i = 1; i < E_NUM; ++i) if (row0 >= pad_off[i]) e = i;
  const int iBase = blockIdx.x * 64;

  const int srcChunk = (lane & 7) ^ ((lane >> 3) & 7);

  const unsigned short* agbase[4];
#pragma unroll
  for (int j = 0; j < 4; ++j) {
    int r = j * 32 + wave * 8 + (lane >> 3);
    int p = perm[row0 + r];
    int tok = (p < 0) ? 0 : (p >> 1);
    agbase[j] = xbf + (size_t)tok * H_DIM + srcChunk * 8;
  }
  const unsigned short* bgbase[4];
#pragma unroll
  for (int j = 0; j < 4; ++j) {
    int brow = j * 32 + wave * 8 + (lane >> 3);
    int seg = brow >> 5, half = seg & 1;
    int col = iBase + (seg >> 1) * 32 + (brow & 31);
    bgbase[j] = w13b + ((size_t)e * 2 * I_DIM + half * I_DIM + col) * H_DIM + srcChunk * 8;
  }

  f32x4 acc[4][4];
#pragma unroll
  for (int mi = 0; mi < 4; ++mi)
#pragma unroll
    for (int ni = 0; ni < 4; ++ni) acc[mi][ni] = (f32x4)(0.f);

  const int wm = wave >> 1, wn = wave & 1;
  const int ml = lane & 15, quad = lane >> 4;

  for (int k0 = 0; k0 < H_DIM; k0 += 64) {
    __syncthreads();
#pragma unroll
    for (int j = 0; j < 4; ++j)
      async_copy16(agbase[j] + k0, a_lds + (j * 256 + wave * 64) * 8);
#pragma unroll
    for (int j = 0; j < 4; ++j)
      async_copy16(bgbase[j] + k0, b_lds + (j * 256 + wave * 64) * 8);
    __syncthreads();
#pragma unroll
    for (int ks = 0; ks < 2; ++ks) {
      const int ch = ((ks * 4 + quad) ^ (ml & 7)) * 8;
      bf16x8 af[4], bfr[4];
#pragma unroll
      for (int mi = 0; mi < 4; ++mi)
        af[mi] = *(const bf16x8*)(a_lds + (wm * 64 + mi * 16 + ml) * 64 + ch);
#pragma unroll
      for (int ni = 0; ni < 4; ++ni)
        bfr[ni] = *(const bf16x8*)(b_lds + (wn * 64 + ni * 16 + ml) * 64 + ch);
#pragma unroll
      for (int mi = 0; mi < 4; ++mi)
#pragma unroll
        for (int ni = 0; ni < 4; ++ni)
          acc[mi][ni] = __builtin_amdgcn_mfma_f32_16x16x32_bf16(af[mi], bfr[ni], acc[mi][ni], 0, 0, 0);
    }
  }
#pragma unroll
  for (int mi = 0; mi < 4; ++mi) {
#pragma unroll
    for (int nc = 0; nc < 2; ++nc) {
      f32x4 g = acc[mi][nc];
      f32x4 uu = acc[mi][nc + 2];
#pragma unroll
      for (int r = 0; r < 4; ++r) {
        int row = row0 + wm * 64 + mi * 16 + quad * 4 + r;
        int col = iBase + wn * 32 + nc * 16 + ml;
        float gg = g[r];
        float hv = 0.5f * gg * (1.f + erff(gg * 0.7071067811865475f)) * uu[r];
        h_buf[(size_t)row * I_DIM + col] = f2b(hv);
      }
    }
  }
}

// ---------------- GEMM2: out[tok] += cw * (h[slot] @ w2[e]^T) ----------------
// Grid dim3(16, 72), col-fast (same XCD-affinity argument as gemm1).
// 128 rows x 64 cols per block; wave owns 32 rows x 64 cols. Atomic f32
// epilogue (2 writers/address max) replaces the separate combine kernel —
// saves a dispatch (~13 us fixed) and skips the bf16 rounding of y.
__global__ __launch_bounds__(256, 2) void k_gemm2(
    const unsigned short* __restrict__ h_buf,
    const unsigned short* __restrict__ w2b,
    const int* __restrict__ perm, const int* __restrict__ pad_off,
    const float* __restrict__ cw, float* __restrict__ out) {
  __shared__ __align__(16) unsigned short a_lds[128 * 64];
  __shared__ __align__(16) unsigned short b_lds[64 * 64];
  __shared__ int s_tok[128];
  __shared__ float s_cw[128];
  const int tid = threadIdx.x;
  const int wave = tid >> 6, lane = tid & 63;
  const int row0 = blockIdx.y * 128;
  if (row0 >= pad_off[E_NUM]) return;
  int e = 0;
#pragma unroll
  for (int i = 1; i < E_NUM; ++i) if (row0 >= pad_off[i]) e = i;
  const int cBase = blockIdx.x * 64;
  if (tid < 128) {
    int p = perm[row0 + tid];
    s_tok[tid] = (p < 0) ? -1 : (p >> 1);
    s_cw[tid] = (p < 0) ? 0.f : cw[p];
  }
  const int srcChunk = (lane & 7) ^ ((lane >> 3) & 7);

  const unsigned short* agbase[4];
#pragma unroll
  for (int j = 0; j < 4; ++j) {
    int r = j * 32 + wave * 8 + (lane >> 3);
    agbase[j] = h_buf + (size_t)(row0 + r) * I_DIM + srcChunk * 8;
  }
  const unsigned short* bgbase[2];
#pragma unroll
  for (int j = 0; j < 2; ++j) {
    int brow = j * 32 + wave * 8 + (lane >> 3);
    bgbase[j] = w2b + ((size_t)e * H_DIM + cBase + brow) * I_DIM + srcChunk * 8;
  }
  f32x4 acc[2][4];
#pragma unroll
  for (int mi = 0; mi < 2; ++mi)
#pragma unroll
    for (int ni = 0; ni < 4; ++ni) acc[mi][ni] = (f32x4)(0.f);
  const int ml = lane & 15, quad = lane >> 4;

  for (int k0 = 0; k0 < I_DIM; k0 += 64) {
    __syncthreads();
#pragma unroll
    for (int j = 0; j < 4; ++j)
      async_copy16(agbase[j] + k0, a_lds + (j * 256 + wave * 64) * 8);
#pragma unroll
    for (int j = 0; j < 2; ++j)
      async_copy16(bgbase[j] + k0, b_lds + (j * 256 + wave * 64) * 8);
    __syncthreads();
#pragma unroll
    for (int ks = 0; ks < 2; ++ks) {
      const int ch = ((ks * 4 + quad) ^ (ml & 7)) * 8;
      bf16x8 af[2], bfr[4];
#pragma unroll
      for (int mi = 0; mi < 2; ++mi)
        af[mi] = *(const bf16x8*)(a_lds + (wave * 32 + mi * 16 + ml) * 64 + ch);
#pragma unroll
      for (int ni = 0; ni < 4; ++ni)
        bfr[ni] = *(const bf16x8*)(b_lds + (ni * 16 + ml) * 64 + ch);
#pragma unroll
      for (int mi = 0; mi < 2; ++mi)
#pragma unroll
        for (int ni = 0; ni < 4; ++ni)
          acc[mi][ni] = __builtin_amdgcn_mfma_f32_16x16x32_bf16(af[mi], bfr[ni], acc[mi][ni], 0, 0, 0);
    }
  }
#pragma unroll
  for (int mi = 0; mi < 2; ++mi) {
#pragma unroll
    for (int ni = 0; ni < 4; ++ni) {
#pragma unroll
      for (int r = 0; r < 4; ++r) {
        int lrow = wave * 32 + mi * 16 + quad * 4 + r;
        int tok = s_tok[lrow];
        if (tok >= 0)
          atomicAdd(&out[(size_t)tok * H_DIM + cBase + ni * 16 + ml],
                    s_cw[lrow] * acc[mi][ni][r]);
      }
    }
  }
}

extern "C" void kernel_launch(void* const* d_in, const int* in_sizes, int n_in,
                              void* d_out, int out_size, void* d_ws, size_t ws_size,
                              hipStream_t stream) {
  const float* x      = (const float*)d_in[0];
  const float* logits = (const float*)d_in[1];
  const float* scale  = (const float*)d_in[2];
  const float* w13    = (const float*)d_in[3];
  const float* w2     = (const float*)d_in[4];
  float* out = (float*)d_out;

  char* ws = (char*)d_ws;
  int*   pad_off = (int*)(ws + 128);              // 9 ints
  int*   cnt     = (int*)(ws + 1024);             // RBLK*E ints
  int*   tids    = (int*)(ws + 4096);             // T*2 ints (32 KB)
  float* cw      = (float*)(ws + 65536);          // T*2 floats (32 KB)
  int*   perm    = (int*)(ws + 131072);           // PAD_CAP ints (36 KB)
  int*   inv     = (int*)(ws + 196608);           // T*2 ints (32 KB)
  unsigned short* xb    = (unsigned short*)(ws + 0x40000);    // 8 MB
  unsigned short* h_buf = (unsigned short*)(ws + 0x900000);   // 18.9 MB
  unsigned short* w13b  = (unsigned short*)(ws + 0x1C00000);  // 32 MB
  unsigned short* w2b   = (unsigned short*)(ws + 0x3C00000);  // 16 MB (total 76 MB)

  k_prep<<<RBLK + CONVB + ZEROB, 256, 0, stream>>>(x, logits, scale, w13, w2,
                                                   xb, w13b, w2b, tids, cw, cnt, out);
  k_scatter16<<<RBLK, 256, 0, stream>>>(cnt, tids, pad_off, perm, inv);
  k_gemm1<<<dim3(16, PAD_CAP / 128), 256, 0, stream>>>(xb, w13b, perm, pad_off, h_buf);
  k_gemm2<<<dim3(16, PAD_CAP / 128), 256, 0, stream>>>(h_buf, w2b, perm, pad_off, cw, out);
}

// Round 8
// 245.734 us; speedup vs baseline: 1.0196x; 1.0196x over previous
//
#include <hip/hip_runtime.h>
#include <hip/hip_bf16.h>

#define T_TOK 4096
#define H_DIM 1024
#define E_NUM 8
#define I_DIM 1024
#define PAD_CAP 9216   // 72 * 128 >= 8192 + 8*127
#define RBLK 16        // router blocks (256 tokens each)
#define CONVB 14336    // conversion blocks (2048 elems each)
#define ZEROB 2048     // out-zeroing blocks (2048 floats each)

typedef __attribute__((ext_vector_type(4))) float f32x4;
typedef __attribute__((ext_vector_type(8))) short bf16x8;

__device__ __forceinline__ unsigned short f2b(float f) {
  union { float f; unsigned int u; } v; v.f = f;
  unsigned int r = v.u + 0x7fffu + ((v.u >> 16) & 1u);  // RNE to bf16
  return (unsigned short)(r >> 16);
}

__device__ __forceinline__ void async_copy16(const void* g, void* l) {
  __builtin_amdgcn_global_load_lds(
      (const __attribute__((address_space(1))) void*)g,
      (__attribute__((address_space(3))) void*)l, 16, 0, 0);
}

// ---------------- prep: route-count (16 blks) + f32->bf16 conv + out-zero ------
// NOTE (r7 post-mortem): wall-time slop is a CONSTANT ~100 us/iteration
// (harness restore+poison), NOT ~13 us/dispatch — fusing dispatches further
// buys nothing. Only kernel time matters now.
__global__ __launch_bounds__(256) void k_prep(
    const float* __restrict__ x, const float* __restrict__ logits,
    const float* __restrict__ scale,
    const float* __restrict__ w13, const float* __restrict__ w2,
    unsigned short* __restrict__ xb, unsigned short* __restrict__ w13b,
    unsigned short* __restrict__ w2b,
    int* __restrict__ tids, float* __restrict__ cw, int* __restrict__ cnt,
    float* __restrict__ out) {
  const int b = blockIdx.x;
  const int tid = threadIdx.x;
  if (b < RBLK) {
    __shared__ int s_cnt[E_NUM];
    if (tid < E_NUM) s_cnt[tid] = 0;
    __syncthreads();
    int t = b * 256 + tid;
    float l[E_NUM];
    *(float4*)(l)     = *(const float4*)(logits + (size_t)t * E_NUM);
    *(float4*)(l + 4) = *(const float4*)(logits + (size_t)t * E_NUM + 4);
    float m = l[0];
#pragma unroll
    for (int i = 1; i < E_NUM; ++i) m = fmaxf(m, l[i]);
    float p[E_NUM]; float s = 0.f;
#pragma unroll
    for (int i = 0; i < E_NUM; ++i) { p[i] = expf(l[i] - m); s += p[i]; }
    int i0 = 0; float b0 = l[0];
#pragma unroll
    for (int i = 1; i < E_NUM; ++i) if (l[i] > b0) { b0 = l[i]; i0 = i; }
    int i1 = -1; float b1 = -1e30f;
#pragma unroll
    for (int i = 0; i < E_NUM; ++i) if (i != i0 && l[i] > b1) { b1 = l[i]; i1 = i; }
    float g0 = p[i0] / s, g1 = p[i1] / s;
    float r = g0 + g1;
    cw[t * 2]     = g0 / r * scale[i0];
    cw[t * 2 + 1] = g1 / r * scale[i1];
    tids[t * 2] = i0; tids[t * 2 + 1] = i1;
    atomicAdd(&s_cnt[i0], 1);
    atomicAdd(&s_cnt[i1], 1);
    __syncthreads();
    if (tid < E_NUM) cnt[b * E_NUM + tid] = s_cnt[tid];
    return;
  }
  if (b < RBLK + CONVB) {
    const int cb = b - RBLK;
    const float* src; unsigned short* dst; size_t base;
    if (cb < 2048)       { src = x;   dst = xb;   base = (size_t)cb * 2048; }
    else if (cb < 10240) { src = w13; dst = w13b; base = (size_t)(cb - 2048) * 2048; }
    else                 { src = w2;  dst = w2b;  base = (size_t)(cb - 10240) * 2048; }
    size_t i = base + (size_t)tid * 8;
    float4 f0 = *(const float4*)(src + i);
    float4 f1 = *(const float4*)(src + i + 4);
    uint4 pk;
    pk.x = (unsigned)f2b(f0.x) | ((unsigned)f2b(f0.y) << 16);
    pk.y = (unsigned)f2b(f0.z) | ((unsigned)f2b(f0.w) << 16);
    pk.z = (unsigned)f2b(f1.x) | ((unsigned)f2b(f1.y) << 16);
    pk.w = (unsigned)f2b(f1.z) | ((unsigned)f2b(f1.w) << 16);
    *(uint4*)(dst + i) = pk;
    return;
  }
  // zero out (gemm2 accumulates into it atomically)
  const int zb = b - RBLK - CONVB;
  size_t i = (size_t)zb * 2048 + (size_t)tid * 8;
  float4 z = {0.f, 0.f, 0.f, 0.f};
  *(float4*)(out + i) = z;
  *(float4*)(out + i + 4) = z;
}

// ---------------- scatter: redundant in-block scan + rank -> perm/inv + pad-fill
__global__ __launch_bounds__(256) void k_scatter16(
    const int* __restrict__ cnt, const int* __restrict__ tids,
    int* __restrict__ pad_off, int* __restrict__ perm, int* __restrict__ inv) {
  __shared__ int l_cnt[E_NUM];
  __shared__ int s_base[E_NUM];                 // this block's start per expert
  __shared__ int s_off[E_NUM + 1], s_tot[E_NUM];
  const int b = blockIdx.x, tid = threadIdx.x;
  if (tid < E_NUM) l_cnt[tid] = 0;
  if (tid == 0) {
    int off = 0;
    for (int e = 0; e < E_NUM; ++e) {
      int tot = 0, mine = 0;
      for (int k = 0; k < RBLK; ++k) {
        if (k == b) mine = tot;
        tot += cnt[k * E_NUM + e];
      }
      s_tot[e] = tot;
      s_off[e] = off;
      s_base[e] = off + mine;
      off += (tot + 127) & ~127;
    }
    s_off[E_NUM] = off;
    if (b == 0) {
      for (int e = 0; e <= E_NUM; ++e) pad_off[e] = s_off[e];
    }
  }
  __syncthreads();
  int t = b * 256 + tid;
  int i0 = tids[t * 2], i1 = tids[t * 2 + 1];
  int r0 = atomicAdd(&l_cnt[i0], 1);
  int s0 = s_base[i0] + r0;
  perm[s0] = t * 2; inv[t * 2] = s0;
  int r1 = atomicAdd(&l_cnt[i1], 1);
  int s1 = s_base[i1] + r1;
  perm[s1] = t * 2 + 1; inv[t * 2 + 1] = s1;
  int gid = b * 256 + tid;
  for (int e = 0; e < E_NUM; ++e) {
    int start = s_off[e] + s_tot[e];
    int end   = s_off[e + 1];
    for (int i = start + gid; i < end; i += RBLK * 256) perm[i] = -1;
  }
}

// ---------------- GEMM1: h = gelu(x@w1^T) * (x@w3^T) ----------------
// Grid dim3(16, 72), blockIdx.x = col-block (FAST): round-robin dispatch pins
// cb -> XCD, so each (expert, cb) w13 slice stays in one XCD's L2. Do NOT
// swizzle blockIdx (round 3: FETCH 194 MB, 2x slower).
// __launch_bounds__(256, 2): (256,4) squeezed VGPRs 72->64 and cost 55->94 us.
__global__ __launch_bounds__(256, 2) void k_gemm1(
    const unsigned short* __restrict__ xbf,
    const unsigned short* __restrict__ w13b,
    const int* __restrict__ perm, const int* __restrict__ pad_off,
    unsigned short* __restrict__ h_buf) {
  __shared__ __align__(16) unsigned short a_lds[128 * 64];
  __shared__ __align__(16) unsigned short b_lds[128 * 64];
  const int tid = threadIdx.x;
  const int wave = tid >> 6, lane = tid & 63;
  const int row0 = blockIdx.y * 128;
  if (row0 >= pad_off[E_NUM]) return;
  int e = 0;
#pragma unroll
  for (int i = 1; i < E_NUM; ++i) if (row0 >= pad_off[i]) e = i;
  const int iBase = blockIdx.x * 64;

  const int srcChunk = (lane & 7) ^ ((lane >> 3) & 7);

  const unsigned short* agbase[4];
#pragma unroll
  for (int j = 0; j < 4; ++j) {
    int r = j * 32 + wave * 8 + (lane >> 3);
    int p = perm[row0 + r];
    int tok = (p < 0) ? 0 : (p >> 1);
    agbase[j] = xbf + (size_t)tok * H_DIM + srcChunk * 8;
  }
  const unsigned short* bgbase[4];
#pragma unroll
  for (int j = 0; j < 4; ++j) {
    int brow = j * 32 + wave * 8 + (lane >> 3);
    int seg = brow >> 5, half = seg & 1;
    int col = iBase + (seg >> 1) * 32 + (brow & 31);
    bgbase[j] = w13b + ((size_t)e * 2 * I_DIM + half * I_DIM + col) * H_DIM + srcChunk * 8;
  }

  f32x4 acc[4][4];
#pragma unroll
  for (int mi = 0; mi < 4; ++mi)
#pragma unroll
    for (int ni = 0; ni < 4; ++ni) acc[mi][ni] = (f32x4)(0.f);

  const int wm = wave >> 1, wn = wave & 1;
  const int ml = lane & 15, quad = lane >> 4;

  for (int k0 = 0; k0 < H_DIM; k0 += 64) {
    __syncthreads();
#pragma unroll
    for (int j = 0; j < 4; ++j)
      async_copy16(agbase[j] + k0, a_lds + (j * 256 + wave * 64) * 8);
#pragma unroll
    for (int j = 0; j < 4; ++j)
      async_copy16(bgbase[j] + k0, b_lds + (j * 256 + wave * 64) * 8);
    __syncthreads();
#pragma unroll
    for (int ks = 0; ks < 2; ++ks) {
      const int ch = ((ks * 4 + quad) ^ (ml & 7)) * 8;
      bf16x8 af[4], bfr[4];
#pragma unroll
      for (int mi = 0; mi < 4; ++mi)
        af[mi] = *(const bf16x8*)(a_lds + (wm * 64 + mi * 16 + ml) * 64 + ch);
#pragma unroll
      for (int ni = 0; ni < 4; ++ni)
        bfr[ni] = *(const bf16x8*)(b_lds + (wn * 64 + ni * 16 + ml) * 64 + ch);
#pragma unroll
      for (int mi = 0; mi < 4; ++mi)
#pragma unroll
        for (int ni = 0; ni < 4; ++ni)
          acc[mi][ni] = __builtin_amdgcn_mfma_f32_16x16x32_bf16(af[mi], bfr[ni], acc[mi][ni], 0, 0, 0);
    }
  }
#pragma unroll
  for (int mi = 0; mi < 4; ++mi) {
#pragma unroll
    for (int nc = 0; nc < 2; ++nc) {
      f32x4 g = acc[mi][nc];
      f32x4 uu = acc[mi][nc + 2];
#pragma unroll
      for (int r = 0; r < 4; ++r) {
        int row = row0 + wm * 64 + mi * 16 + quad * 4 + r;
        int col = iBase + wn * 32 + nc * 16 + ml;
        float gg = g[r];
        float hv = 0.5f * gg * (1.f + erff(gg * 0.7071067811865475f)) * uu[r];
        h_buf[(size_t)row * I_DIM + col] = f2b(hv);
      }
    }
  }
}

// ---------------- GEMM2: out[tok] += cw * (h[slot] @ w2[e]^T) ----------------
// Grid dim3(16, 72), col-fast. 128 rows x 64 cols per block, BK=128:
// r7 showed gemm2 ~80% waiting (MfmaUtil 12%, VALU 8%) at BK=64's 16
// barrier-drain iterations; BK=128 halves drains and doubles per-iter MFMA
// (32/wave, matching gemm1's amortization). LDS 48 KB -> 3 blocks/CU.
// Row stride 128 shorts; 16 chunks/row, XOR-swizzle low 3 chunk bits by
// (row&7) — 8-lane read phases stay conflict-free (measured 0 conflicts).
__global__ __launch_bounds__(256, 2) void k_gemm2(
    const unsigned short* __restrict__ h_buf,
    const unsigned short* __restrict__ w2b,
    const int* __restrict__ perm, const int* __restrict__ pad_off,
    const float* __restrict__ cw, float* __restrict__ out) {
  __shared__ __align__(16) unsigned short a_lds[128 * 128];
  __shared__ __align__(16) unsigned short b_lds[64 * 128];
  __shared__ int s_tok[128];
  __shared__ float s_cw[128];
  const int tid = threadIdx.x;
  const int wave = tid >> 6, lane = tid & 63;
  const int row0 = blockIdx.y * 128;
  if (row0 >= pad_off[E_NUM]) return;
  int e = 0;
#pragma unroll
  for (int i = 1; i < E_NUM; ++i) if (row0 >= pad_off[i]) e = i;
  const int cBase = blockIdx.x * 64;
  if (tid < 128) {
    int p = perm[row0 + tid];
    s_tok[tid] = (p < 0) ? -1 : (p >> 1);
    s_cw[tid] = (p < 0) ? 0.f : cw[p];
  }
  // staging geometry (BK=128): per copy-round a wave covers 4 rows x 16 chunks;
  // lane -> row_in_group = lane>>4, chunk position = lane&15.
  const int rin = wave * 4 + (lane >> 4);            // row within 16-row group
  const int srcChunk = (lane & 15) ^ (rin & 7);      // low-3-bit XOR swizzle

  const unsigned short* agbase[8];
#pragma unroll
  for (int j = 0; j < 8; ++j) {
    int r = j * 16 + rin;
    agbase[j] = h_buf + (size_t)(row0 + r) * I_DIM + srcChunk * 8;
  }
  const unsigned short* bgbase[4];
#pragma unroll
  for (int j = 0; j < 4; ++j) {
    int r = j * 16 + rin;
    bgbase[j] = w2b + ((size_t)e * H_DIM + cBase + r) * I_DIM + srcChunk * 8;
  }
  f32x4 acc[2][4];
#pragma unroll
  for (int mi = 0; mi < 2; ++mi)
#pragma unroll
    for (int ni = 0; ni < 4; ++ni) acc[mi][ni] = (f32x4)(0.f);
  const int ml = lane & 15, quad = lane >> 4;

  for (int k0 = 0; k0 < I_DIM; k0 += 128) {
    __syncthreads();
#pragma unroll
    for (int j = 0; j < 8; ++j)
      async_copy16(agbase[j] + k0, a_lds + (j * 16 + wave * 4) * 128 + lane * 8);
#pragma unroll
    for (int j = 0; j < 4; ++j)
      async_copy16(bgbase[j] + k0, b_lds + (j * 16 + wave * 4) * 128 + lane * 8);
    __syncthreads();
#pragma unroll
    for (int ks = 0; ks < 4; ++ks) {
      const int ch = ((ks * 4 + quad) ^ (ml & 7)) * 8;
      bf16x8 af[2], bfr[4];
#pragma unroll
      for (int mi = 0; mi < 2; ++mi)
        af[mi] = *(const bf16x8*)(a_lds + (wave * 32 + mi * 16 + ml) * 128 + ch);
#pragma unroll
      for (int ni = 0; ni < 4; ++ni)
        bfr[ni] = *(const bf16x8*)(b_lds + (ni * 16 + ml) * 128 + ch);
#pragma unroll
      for (int mi = 0; mi < 2; ++mi)
#pragma unroll
        for (int ni = 0; ni < 4; ++ni)
          acc[mi][ni] = __builtin_amdgcn_mfma_f32_16x16x32_bf16(af[mi], bfr[ni], acc[mi][ni], 0, 0, 0);
    }
  }
#pragma unroll
  for (int mi = 0; mi < 2; ++mi) {
#pragma unroll
    for (int ni = 0; ni < 4; ++ni) {
#pragma unroll
      for (int r = 0; r < 4; ++r) {
        int lrow = wave * 32 + mi * 16 + quad * 4 + r;
        int tok = s_tok[lrow];
        if (tok >= 0)
          atomicAdd(&out[(size_t)tok * H_DIM + cBase + ni * 16 + ml],
                    s_cw[lrow] * acc[mi][ni][r]);
      }
    }
  }
}

extern "C" void kernel_launch(void* const* d_in, const int* in_sizes, int n_in,
                              void* d_out, int out_size, void* d_ws, size_t ws_size,
                              hipStream_t stream) {
  const float* x      = (const float*)d_in[0];
  const float* logits = (const float*)d_in[1];
  const float* scale  = (const float*)d_in[2];
  const float* w13    = (const float*)d_in[3];
  const float* w2     = (const float*)d_in[4];
  float* out = (float*)d_out;

  char* ws = (char*)d_ws;
  int*   pad_off = (int*)(ws + 128);              // 9 ints
  int*   cnt     = (int*)(ws + 1024);             // RBLK*E ints
  int*   tids    = (int*)(ws + 4096);             // T*2 ints (32 KB)
  float* cw      = (float*)(ws + 65536);          // T*2 floats (32 KB)
  int*   perm    = (int*)(ws + 131072);           // PAD_CAP ints (36 KB)
  int*   inv     = (int*)(ws + 196608);           // T*2 ints (32 KB)
  unsigned short* xb    = (unsigned short*)(ws + 0x40000);    // 8 MB
  unsigned short* h_buf = (unsigned short*)(ws + 0x900000);   // 18.9 MB
  unsigned short* w13b  = (unsigned short*)(ws + 0x1C00000);  // 32 MB
  unsigned short* w2b   = (unsigned short*)(ws + 0x3C00000);  // 16 MB (total 76 MB)

  k_prep<<<RBLK + CONVB + ZEROB, 256, 0, stream>>>(x, logits, scale, w13, w2,
                                                   xb, w13b, w2b, tids, cw, cnt, out);
  k_scatter16<<<RBLK, 256, 0, stream>>>(cnt, tids, pad_off, perm, inv);
  k_gemm1<<<dim3(16, PAD_CAP / 128), 256, 0, stream>>>(xb, w13b, perm, pad_off, h_buf);
  k_gemm2<<<dim3(16, PAD_CAP / 128), 256, 0, stream>>>(h_buf, w2b, perm, pad_off, cw, out);
}